// Round 1
// baseline (625.315 us; speedup 1.0000x reference)
//
#include <hip/hip_runtime.h>
#include <hip/hip_bf16.h>
#include <stdint.h>

#define B_DIM 8192
#define IN_DIMC 1024
#define HIDC 1024
#define K_DIM 1024
#define ODE_STEPS 6

typedef float f32x4 __attribute__((ext_vector_type(4)));
typedef short bf16x8 __attribute__((ext_vector_type(8)));

__device__ __forceinline__ float bf2f(unsigned short u) {
    union { unsigned int u; float f; } c; c.u = ((unsigned int)u) << 16; return c.f;
}
__device__ __forceinline__ unsigned short f2bf(float f) {
    union { float f; unsigned int u; } c; c.f = f;
    unsigned int u = c.u;
    return (unsigned short)((u + 0x7fffu + ((u >> 16) & 1u)) >> 16);
}

// ---------------- convert all f32 inputs to bf16 in workspace ----------------
constexpr size_t XN    = (size_t)B_DIM * IN_DIMC;        // 8388608
constexpr size_t HN    = (size_t)B_DIM * HIDC;           // 8388608
constexpr size_t WINN  = (size_t)HIDC * IN_DIMC;         // 1048576
constexpr size_t WRECN = (size_t)HIDC * HIDC;            // 1048576
constexpr size_t WGN   = (size_t)HIDC * (IN_DIMC + HIDC);// 2097152
constexpr size_t TOTQ  = (XN + HN + WINN + WRECN + WGN) / 4; // 5242880

__global__ __launch_bounds__(256) void convert_all(
    const float* __restrict__ x, const float* __restrict__ h,
    const float* __restrict__ win, const float* __restrict__ wrec,
    const float* __restrict__ wgate,
    unsigned short* __restrict__ x_bf, unsigned short* __restrict__ h_bf,
    unsigned short* __restrict__ win_bf, unsigned short* __restrict__ wrec_bf,
    unsigned short* __restrict__ wgx_bf, unsigned short* __restrict__ wgh_bf)
{
    size_t q = (size_t)blockIdx.x * 256 + threadIdx.x;
    if (q >= TOTQ) return;
    size_t e = q * 4;
    const float* src; unsigned short* dst; size_t si, di;
    if (e < XN)                          { src = x;    si = e;                       dst = x_bf;    di = si; }
    else if (e < XN + HN)                { src = h;    si = e - XN;                  dst = h_bf;    di = si; }
    else if (e < XN + HN + WINN)         { src = win;  si = e - XN - HN;             dst = win_bf;  di = si; }
    else if (e < XN + HN + WINN + WRECN) { src = wrec; si = e - XN - HN - WINN;      dst = wrec_bf; di = si; }
    else {
        size_t i = e - XN - HN - WINN - WRECN;
        size_t row = i >> 11, col = i & 2047;
        src = wgate; si = i;
        if (col < 1024) { dst = wgx_bf; di = row * 1024 + col; }
        else            { dst = wgh_bf; di = row * 1024 + (col - 1024); }
    }
    float4 v = *(const float4*)(src + si);
    ushort4 o;
    o.x = f2bf(v.x); o.y = f2bf(v.y); o.z = f2bf(v.z); o.w = f2bf(v.w);
    *(ushort4*)(dst + di) = o;
}

// ---------------- fused dual-GEMM (m97 structure) ----------------
// Computes acc1 = A @ B1^T, acc2 = A @ B2^T  (A: M x K bf16, B: N x K bf16)
// STEP=false: epilogue writes bf16 (acc1+bias1)->GX_out, (acc2+bias2)->ID_out
// STEP=true : epilogue does the LTC ODE sub-step update
constexpr int BM = 128, BN = 128, BK = 32;
constexpr int NT = HIDC / BN; // 8

__device__ __forceinline__ void gload_lds16(const void* g, void* l) {
    __builtin_amdgcn_global_load_lds(
        (const __attribute__((address_space(1))) void*)g,
        (__attribute__((address_space(3))) void*)l, 16, 0, 0);
}

template<bool STEP>
__global__ __launch_bounds__(256, 2) void ltc_gemm(
    const unsigned short* __restrict__ A,
    const unsigned short* __restrict__ B1,
    const unsigned short* __restrict__ B2,
    const unsigned short* __restrict__ GX, const unsigned short* __restrict__ ID,
    const float* __restrict__ h_in, const float* __restrict__ log_tau,
    float* __restrict__ h_out, float* __restrict__ h_out2,
    unsigned short* __restrict__ hbf_out,
    const float* __restrict__ bias1, const float* __restrict__ bias2,
    unsigned short* __restrict__ GX_out, unsigned short* __restrict__ ID_out)
{
    __shared__ __attribute__((aligned(16))) unsigned short lA[BM * BK];
    __shared__ __attribute__((aligned(16))) unsigned short lB1[BN * BK];
    __shared__ __attribute__((aligned(16))) unsigned short lB2[BN * BK];

    const int tid = threadIdx.x;
    const int w = tid >> 6, l = tid & 63;
    const int mt = blockIdx.x / NT, nt = blockIdx.x % NT;
    const int m0 = mt * BM, n0 = nt * BN;
    const int wm = (w >> 1) * 64, wn = (w & 1) * 64;
    const int lrow = l >> 2, lcol = (l & 3) * 8;   // staging: 16 rows x 32 cols per instr
    const int srow = w * 32;                        // this wave stages rows [srow, srow+32)
    const int lm = l & 15, lq = l >> 4;

    f32x4 acc1[4][4], acc2[4][4];
    f32x4 z4 = {0.f, 0.f, 0.f, 0.f};
    #pragma unroll
    for (int i = 0; i < 4; i++)
        #pragma unroll
        for (int j = 0; j < 4; j++) { acc1[i][j] = z4; acc2[i][j] = z4; }

    for (int k0 = 0; k0 < K_DIM; k0 += BK) {
        #pragma unroll
        for (int i = 0; i < 2; i++) {
            int rr = srow + i * 16;
            gload_lds16(A  + (size_t)(m0 + rr + lrow) * K_DIM + k0 + lcol, &lA [rr * BK]);
            gload_lds16(B1 + (size_t)(n0 + rr + lrow) * K_DIM + k0 + lcol, &lB1[rr * BK]);
            gload_lds16(B2 + (size_t)(n0 + rr + lrow) * K_DIM + k0 + lcol, &lB2[rr * BK]);
        }
        __syncthreads();

        bf16x8 af[4], f1[4], f2[4];
        #pragma unroll
        for (int mi = 0; mi < 4; mi++)
            af[mi] = *(const bf16x8*)&lA[(wm + mi * 16 + lm) * BK + lq * 8];
        #pragma unroll
        for (int ni = 0; ni < 4; ni++) {
            f1[ni] = *(const bf16x8*)&lB1[(wn + ni * 16 + lm) * BK + lq * 8];
            f2[ni] = *(const bf16x8*)&lB2[(wn + ni * 16 + lm) * BK + lq * 8];
        }
        #pragma unroll
        for (int mi = 0; mi < 4; mi++)
            #pragma unroll
            for (int ni = 0; ni < 4; ni++) {
                acc1[mi][ni] = __builtin_amdgcn_mfma_f32_16x16x32_bf16(af[mi], f1[ni], acc1[mi][ni], 0, 0, 0);
                acc2[mi][ni] = __builtin_amdgcn_mfma_f32_16x16x32_bf16(af[mi], f2[ni], acc2[mi][ni], 0, 0, 0);
            }
        __syncthreads();
    }

    // epilogue: C/D layout col=lane&15, row=(lane>>4)*4+r  [m89-verified]
    constexpr float subdt = 1.0f / (float)ODE_STEPS;
    #pragma unroll
    for (int mi = 0; mi < 4; mi++) {
        #pragma unroll
        for (int ni = 0; ni < 4; ni++) {
            const int gmb = m0 + wm + mi * 16 + lq * 4;
            const int gn  = n0 + wn + ni * 16 + lm;
            if (STEP) {
                const float sc = subdt * __expf(-log_tau[gn]);
                #pragma unroll
                for (int r = 0; r < 4; r++) {
                    size_t idx = (size_t)(gmb + r) * HIDC + gn;
                    float gx = bf2f(GX[idx]) + acc1[mi][ni][r];
                    float dr = bf2f(ID[idx]) + acc2[mi][ni][r];
                    float g  = 1.0f / (1.0f + __expf(-gx));
                    float t  = tanhf(dr);
                    float hv = h_in[idx];
                    float hn = fmaf(sc, g * t - hv, hv);
                    h_out[idx] = hn;
                    hbf_out[idx] = f2bf(hn);
                    if (h_out2) h_out2[idx] = hn;
                }
            } else {
                const float b1 = bias1[gn], b2 = bias2[gn];
                #pragma unroll
                for (int r = 0; r < 4; r++) {
                    size_t idx = (size_t)(gmb + r) * HIDC + gn;
                    GX_out[idx] = f2bf(acc1[mi][ni][r] + b1);
                    ID_out[idx] = f2bf(acc2[mi][ni][r] + b2);
                }
            }
        }
    }
}

extern "C" void kernel_launch(void* const* d_in, const int* in_sizes, int n_in,
                              void* d_out, int out_size, void* d_ws, size_t ws_size,
                              hipStream_t stream)
{
    const float* x    = (const float*)d_in[0];
    const float* h    = (const float*)d_in[1];
    const float* ltau = (const float*)d_in[2];
    const float* winw = (const float*)d_in[3];
    const float* winb = (const float*)d_in[4];
    const float* wrec = (const float*)d_in[5];
    const float* wg   = (const float*)d_in[6];
    const float* wgb  = (const float*)d_in[7];

    char* ws = (char*)d_ws;
    unsigned short* x_bf    = (unsigned short*)ws; ws += XN * 2;
    unsigned short* h_bf0   = (unsigned short*)ws; ws += HN * 2;
    unsigned short* h_bf1   = (unsigned short*)ws; ws += HN * 2;
    unsigned short* win_bf  = (unsigned short*)ws; ws += WINN * 2;
    unsigned short* wrec_bf = (unsigned short*)ws; ws += WRECN * 2;
    unsigned short* wgx_bf  = (unsigned short*)ws; ws += WINN * 2;
    unsigned short* wgh_bf  = (unsigned short*)ws; ws += WRECN * 2;
    unsigned short* GXb     = (unsigned short*)ws; ws += HN * 2;
    unsigned short* IDb     = (unsigned short*)ws; ws += HN * 2;

    float* hout  = (float*)d_out;
    float* hout2 = hout + (size_t)B_DIM * HIDC;

    convert_all<<<(int)(TOTQ / 256), 256, 0, stream>>>(
        x, h, winw, wrec, wg, x_bf, h_bf0, win_bf, wrec_bf, wgx_bf, wgh_bf);

    const int grid = (B_DIM / BM) * NT; // 512
    // pre-loop: GX = x@Wgx^T + wgb ; ID = x@Win^T + winb
    ltc_gemm<false><<<grid, 256, 0, stream>>>(
        x_bf, wgx_bf, win_bf,
        nullptr, nullptr, nullptr, nullptr, nullptr, nullptr, nullptr,
        wgb, winb, GXb, IDb);

    unsigned short* hbf[2] = {h_bf0, h_bf1};
    for (int s = 0; s < ODE_STEPS; s++) {
        const float* hin = (s == 0) ? h : (const float*)hout;
        float* o2 = (s == ODE_STEPS - 1) ? hout2 : nullptr;
        ltc_gemm<true><<<grid, 256, 0, stream>>>(
            hbf[s & 1], wgh_bf, wrec_bf,
            GXb, IDb, hin, ltau, hout, o2, hbf[(s + 1) & 1],
            nullptr, nullptr, nullptr, nullptr);
    }
}

// Round 2
// 555.232 us; speedup vs baseline: 1.1262x; 1.1262x over previous
//
#include <hip/hip_runtime.h>
#include <hip/hip_bf16.h>
#include <stdint.h>

#define B_DIM 8192
#define IN_DIMC 1024
#define HIDC 1024
#define K_DIM 1024
#define ODE_STEPS 6

typedef float f32x4 __attribute__((ext_vector_type(4)));
typedef short bf16x8 __attribute__((ext_vector_type(8)));

__device__ __forceinline__ float bf2f(unsigned short u) {
    union { unsigned int u; float f; } c; c.u = ((unsigned int)u) << 16; return c.f;
}
__device__ __forceinline__ unsigned short f2bf(float f) {
    union { float f; unsigned int u; } c; c.f = f;
    unsigned int u = c.u;
    return (unsigned short)((u + 0x7fffu + ((u >> 16) & 1u)) >> 16);
}
// fast tanh via exp2-based __expf; |x|<~44 safe, clamp handled by saturation of expf
__device__ __forceinline__ float fast_tanh(float x) {
    float e = __expf(2.0f * x);          // e^(2x)
    return 1.0f - 2.0f / (e + 1.0f);
}

// ---------------- convert all f32 inputs to bf16 in workspace ----------------
constexpr size_t XN    = (size_t)B_DIM * IN_DIMC;
constexpr size_t HN    = (size_t)B_DIM * HIDC;
constexpr size_t WINN  = (size_t)HIDC * IN_DIMC;
constexpr size_t WRECN = (size_t)HIDC * HIDC;
constexpr size_t WGN   = (size_t)HIDC * (IN_DIMC + HIDC);
constexpr size_t TOTQ  = (XN + HN + WINN + WRECN + WGN) / 4;

__global__ __launch_bounds__(256) void convert_all(
    const float* __restrict__ x, const float* __restrict__ h,
    const float* __restrict__ win, const float* __restrict__ wrec,
    const float* __restrict__ wgate,
    unsigned short* __restrict__ x_bf, unsigned short* __restrict__ h_bf,
    unsigned short* __restrict__ win_bf, unsigned short* __restrict__ wrec_bf,
    unsigned short* __restrict__ wgx_bf, unsigned short* __restrict__ wgh_bf)
{
    size_t q = (size_t)blockIdx.x * 256 + threadIdx.x;
    if (q >= TOTQ) return;
    size_t e = q * 4;
    const float* src; unsigned short* dst; size_t si, di;
    if (e < XN)                          { src = x;    si = e;                       dst = x_bf;    di = si; }
    else if (e < XN + HN)                { src = h;    si = e - XN;                  dst = h_bf;    di = si; }
    else if (e < XN + HN + WINN)         { src = win;  si = e - XN - HN;             dst = win_bf;  di = si; }
    else if (e < XN + HN + WINN + WRECN) { src = wrec; si = e - XN - HN - WINN;      dst = wrec_bf; di = si; }
    else {
        size_t i = e - XN - HN - WINN - WRECN;
        size_t row = i >> 11, col = i & 2047;
        src = wgate; si = i;
        if (col < 1024) { dst = wgx_bf; di = row * 1024 + col; }
        else            { dst = wgh_bf; di = row * 1024 + (col - 1024); }
    }
    float4 v = *(const float4*)(src + si);
    ushort4 o;
    o.x = f2bf(v.x); o.y = f2bf(v.y); o.z = f2bf(v.z); o.w = f2bf(v.w);
    *(ushort4*)(dst + di) = o;
}

// ---------------- fused dual-GEMM, BM=128 BN=64 (grid 1024, 3 blk/CU) --------
constexpr int BM = 128, BN = 64, BK = 32;
constexpr int NT = HIDC / BN; // 16

__device__ __forceinline__ void gload_lds16(const void* g, void* l) {
    __builtin_amdgcn_global_load_lds(
        (const __attribute__((address_space(1))) void*)g,
        (__attribute__((address_space(3))) void*)l, 16, 0, 0);
}

template<bool STEP>
__global__ __launch_bounds__(256, 3) void ltc_gemm(
    const unsigned short* __restrict__ A,
    const unsigned short* __restrict__ B1,
    const unsigned short* __restrict__ B2,
    const unsigned short* __restrict__ GX, const unsigned short* __restrict__ ID,
    const float* __restrict__ h_in, const float* __restrict__ log_tau,
    float* __restrict__ h_out, float* __restrict__ h_out2,
    unsigned short* __restrict__ hbf_out,
    const float* __restrict__ bias1, const float* __restrict__ bias2,
    unsigned short* __restrict__ GX_out, unsigned short* __restrict__ ID_out)
{
    __shared__ __attribute__((aligned(16))) unsigned short lA[BM * BK];   // 8 KB
    __shared__ __attribute__((aligned(16))) unsigned short lB1[BN * BK];  // 4 KB
    __shared__ __attribute__((aligned(16))) unsigned short lB2[BN * BK];  // 4 KB

    const int tid = threadIdx.x;
    const int w = tid >> 6, l = tid & 63;
    const int mt = blockIdx.x / NT, nt = blockIdx.x % NT;
    const int m0 = mt * BM, n0 = nt * BN;
    const int wm = (w >> 1) * 64, wn = (w & 1) * 32;
    const int lrow = l >> 2, lcol = (l & 3) * 8;   // staging: 16 rows x 32 cols per instr
    const int lm = l & 15, lq = l >> 4;

    f32x4 acc1[4][2], acc2[4][2];
    f32x4 z4 = {0.f, 0.f, 0.f, 0.f};
    #pragma unroll
    for (int i = 0; i < 4; i++)
        #pragma unroll
        for (int j = 0; j < 2; j++) { acc1[i][j] = z4; acc2[i][j] = z4; }

    // staging assignment: each wave stages 32 A-rows + 32 B-rows (2+2 instrs)
    const int arow = w * 32;
    const unsigned short* Bsrc = (w < 2) ? B1 : B2;
    unsigned short* lBdst = (w < 2) ? lB1 : lB2;
    const int brow = (w & 1) * 32;

    for (int k0 = 0; k0 < K_DIM; k0 += BK) {
        #pragma unroll
        for (int i = 0; i < 2; i++) {
            int ra = arow + i * 16;
            int rb = brow + i * 16;
            gload_lds16(A    + (size_t)(m0 + ra + lrow) * K_DIM + k0 + lcol, &lA[ra * BK]);
            gload_lds16(Bsrc + (size_t)(n0 + rb + lrow) * K_DIM + k0 + lcol, &lBdst[rb * BK]);
        }
        __syncthreads();

        bf16x8 af[4], f1[2], f2[2];
        #pragma unroll
        for (int mi = 0; mi < 4; mi++)
            af[mi] = *(const bf16x8*)&lA[(wm + mi * 16 + lm) * BK + lq * 8];
        #pragma unroll
        for (int ni = 0; ni < 2; ni++) {
            f1[ni] = *(const bf16x8*)&lB1[(wn + ni * 16 + lm) * BK + lq * 8];
            f2[ni] = *(const bf16x8*)&lB2[(wn + ni * 16 + lm) * BK + lq * 8];
        }
        #pragma unroll
        for (int mi = 0; mi < 4; mi++)
            #pragma unroll
            for (int ni = 0; ni < 2; ni++) {
                acc1[mi][ni] = __builtin_amdgcn_mfma_f32_16x16x32_bf16(af[mi], f1[ni], acc1[mi][ni], 0, 0, 0);
                acc2[mi][ni] = __builtin_amdgcn_mfma_f32_16x16x32_bf16(af[mi], f2[ni], acc2[mi][ni], 0, 0, 0);
            }
        __syncthreads();
    }

    // epilogue: C/D layout col=lane&15, row=(lane>>4)*4+r  [m89-verified]
    constexpr float subdt = 1.0f / (float)ODE_STEPS;
    #pragma unroll
    for (int mi = 0; mi < 4; mi++) {
        #pragma unroll
        for (int ni = 0; ni < 2; ni++) {
            const int gmb = m0 + wm + mi * 16 + lq * 4;
            const int gn  = n0 + wn + ni * 16 + lm;
            if (STEP) {
                const float sc = subdt * __expf(-log_tau[gn]);
                #pragma unroll
                for (int r = 0; r < 4; r++) {
                    size_t idx = (size_t)(gmb + r) * HIDC + gn;
                    float gx = bf2f(GX[idx]) + acc1[mi][ni][r];
                    float dr = bf2f(ID[idx]) + acc2[mi][ni][r];
                    float g  = 1.0f / (1.0f + __expf(-gx));
                    float t  = fast_tanh(dr);
                    float hv = h_in[idx];
                    float hn = fmaf(sc, g * t - hv, hv);
                    h_out[idx] = hn;
                    hbf_out[idx] = f2bf(hn);
                    if (h_out2) h_out2[idx] = hn;
                }
            } else {
                const float b1 = bias1[gn], b2 = bias2[gn];
                #pragma unroll
                for (int r = 0; r < 4; r++) {
                    size_t idx = (size_t)(gmb + r) * HIDC + gn;
                    GX_out[idx] = f2bf(acc1[mi][ni][r] + b1);
                    ID_out[idx] = f2bf(acc2[mi][ni][r] + b2);
                }
            }
        }
    }
}

extern "C" void kernel_launch(void* const* d_in, const int* in_sizes, int n_in,
                              void* d_out, int out_size, void* d_ws, size_t ws_size,
                              hipStream_t stream)
{
    const float* x    = (const float*)d_in[0];
    const float* h    = (const float*)d_in[1];
    const float* ltau = (const float*)d_in[2];
    const float* winw = (const float*)d_in[3];
    const float* winb = (const float*)d_in[4];
    const float* wrec = (const float*)d_in[5];
    const float* wg   = (const float*)d_in[6];
    const float* wgb  = (const float*)d_in[7];

    char* ws = (char*)d_ws;
    unsigned short* x_bf    = (unsigned short*)ws; ws += XN * 2;
    unsigned short* h_bf0   = (unsigned short*)ws; ws += HN * 2;
    unsigned short* h_bf1   = (unsigned short*)ws; ws += HN * 2;
    unsigned short* win_bf  = (unsigned short*)ws; ws += WINN * 2;
    unsigned short* wrec_bf = (unsigned short*)ws; ws += WRECN * 2;
    unsigned short* wgx_bf  = (unsigned short*)ws; ws += WINN * 2;
    unsigned short* wgh_bf  = (unsigned short*)ws; ws += WRECN * 2;
    unsigned short* GXb     = (unsigned short*)ws; ws += HN * 2;
    unsigned short* IDb     = (unsigned short*)ws; ws += HN * 2;

    float* hout  = (float*)d_out;
    float* hout2 = hout + (size_t)B_DIM * HIDC;

    convert_all<<<(int)(TOTQ / 256), 256, 0, stream>>>(
        x, h, winw, wrec, wg, x_bf, h_bf0, win_bf, wrec_bf, wgx_bf, wgh_bf);

    const int grid = (B_DIM / BM) * NT; // 1024
    // pre-loop: GX = x@Wgx^T + wgb ; ID = x@Win^T + winb
    ltc_gemm<false><<<grid, 256, 0, stream>>>(
        x_bf, wgx_bf, win_bf,
        nullptr, nullptr, nullptr, nullptr, nullptr, nullptr, nullptr,
        wgb, winb, GXb, IDb);

    unsigned short* hbf[2] = {h_bf0, h_bf1};
    for (int s = 0; s < ODE_STEPS; s++) {
        const float* hin = (s == 0) ? h : (const float*)hout;
        float* o2 = (s == ODE_STEPS - 1) ? hout2 : nullptr;
        ltc_gemm<true><<<grid, 256, 0, stream>>>(
            hbf[s & 1], wgh_bf, wrec_bf,
            GXb, IDb, hin, ltau, hout, o2, hbf[(s + 1) & 1],
            nullptr, nullptr, nullptr, nullptr);
    }
}